// Round 7
// baseline (181.431 us; speedup 1.0000x reference)
//
#include <hip/hip_runtime.h>
#include <math.h>

#define S_LEN 2048
#define DM 1024
#define NH 16
#define DK 64
#define BATCH 2
#define NQ 32          // S_LEN/64 q-tiles
#define MS (BATCH*S_LEN)

typedef __attribute__((ext_vector_type(8))) short bf16x8;
typedef __attribute__((ext_vector_type(4))) float f32x4;
typedef __attribute__((ext_vector_type(16))) float f32x16;
typedef unsigned short u16;
typedef unsigned int u32;

__device__ __forceinline__ u16 f2b(float f) {
  union { float f; u32 u; } x; x.f = f;
  u32 r = x.u + 0x7FFFu + ((x.u >> 16) & 1u);
  return (u16)(r >> 16);
}

__device__ __forceinline__ u32 cvtpk_bf16(float lo, float hi) {
  u32 r;
  asm volatile("v_cvt_pk_bf16_f32 %0, %1, %2" : "=v"(r) : "v"(lo), "v"(hi));
  return r;
}

struct CvtArgs {
  const float* src[7];
  u16* dst[7];
  float scl[7];
  int n4[7];
};

__global__ void cvt_all(CvtArgs a) {
  const int seg = blockIdx.y;
  const float* __restrict__ in = a.src[seg];
  u16* __restrict__ out = a.dst[seg];
  const float s = a.scl[seg];
  const int n4 = a.n4[seg];
  int idx = blockIdx.x * blockDim.x + threadIdx.x;
  int stride = gridDim.x * blockDim.x;
  for (int i = idx; i < n4; i += stride) {
    float4 v = ((const float4*)in)[i];
    ushort4 o;
    o.x = f2b(v.x * s); o.y = f2b(v.y * s); o.z = f2b(v.z * s); o.w = f2b(v.w * s);
    ((ushort4*)out)[i] = o;
  }
}

__device__ __forceinline__ void gload_lds16(const u16* g, u16* l) {
  __builtin_amdgcn_global_load_lds((const __attribute__((address_space(1))) u32*)g,
                                   (__attribute__((address_space(3))) u32*)l, 16, 0, 0);
}

// C[M,N] = A[M,K] * B[N,K]^T  (bf16 in, f32 acc). Double-buffered LDS,
// ONE barrier per K-step: stage(next) issued before compute, __syncthreads
// at iter top drains it (T3 minimal 2-phase).
template<bool OUT_BF16, int BM>
__global__ __launch_bounds__(256) void gemm_bt(
    const u16* __restrict__ A, const u16* __restrict__ B,
    void* __restrict__ Cout, int M, int N, int K)
{
  __shared__ u16 lsA[2][BM*32];
  __shared__ u16 lsB[2][128*32];
  constexpr int MF = BM / 32;
  const int tid = threadIdx.x;
  const int lane = tid & 63;
  const int wid = tid >> 6;
  const int wr = wid >> 1, wc = wid & 1;
  const int m0 = blockIdx.y * BM, n0 = blockIdx.x * 128;

  f32x4 acc[MF][4];
#pragma unroll
  for (int i = 0; i < MF; ++i)
#pragma unroll
    for (int j = 0; j < 4; ++j) acc[i][j] = (f32x4){0.f, 0.f, 0.f, 0.f};

  const int ntiles = K >> 5;

#define GSTAGE(BUF, K0) do { \
    _Pragma("unroll") \
    for (int i = 0; i < BM/64; ++i) { \
      int u = tid + i * 256; \
      gload_lds16(A + (size_t)(m0 + (u >> 2)) * K + (K0) + (u & 3) * 8, &lsA[BUF][u * 8]); \
    } \
    _Pragma("unroll") \
    for (int i = 0; i < 2; ++i) { \
      int u = tid + i * 256; \
      gload_lds16(B + (size_t)(n0 + (u >> 2)) * K + (K0) + (u & 3) * 8, &lsB[BUF][u * 8]); \
    } \
  } while (0)

  GSTAGE(0, 0);
  int cur = 0;
  for (int kt = 0; kt < ntiles; ++kt) {
    __syncthreads();                    // drains stage of buf[cur]; prev reads done
    if (kt + 1 < ntiles) GSTAGE(cur ^ 1, (kt + 1) << 5);   // flies during compute
    bf16x8 af[MF], bfr[4];
    const int kOff = (lane >> 4) * 8;
#pragma unroll
    for (int m = 0; m < MF; ++m)
      af[m] = *(const bf16x8*)&lsA[cur][(wr * (BM/2) + m * 16 + (lane & 15)) * 32 + kOff];
#pragma unroll
    for (int n = 0; n < 4; ++n)
      bfr[n] = *(const bf16x8*)&lsB[cur][(wc * 64 + n * 16 + (lane & 15)) * 32 + kOff];
#pragma unroll
    for (int m = 0; m < MF; ++m)
#pragma unroll
      for (int n = 0; n < 4; ++n)
        acc[m][n] = __builtin_amdgcn_mfma_f32_16x16x32_bf16(af[m], bfr[n], acc[m][n], 0, 0, 0);
    cur ^= 1;
  }
#undef GSTAGE

  const int rbase = m0 + wr * (BM/2) + ((lane >> 4) << 2);
  const int cbase = n0 + wc * 64 + (lane & 15);
#pragma unroll
  for (int m = 0; m < MF; ++m)
#pragma unroll
    for (int n = 0; n < 4; ++n)
#pragma unroll
      for (int j = 0; j < 4; ++j) {
        int r = rbase + m * 16 + j;
        int c = cbase + n * 16;
        if (OUT_BF16)
          ((u16*)Cout)[(size_t)r * N + c] = f2b(acc[m][n][j]);
        else
          ((float*)Cout)[(size_t)r * N + c] = acc[m][n][j];
      }
}

// Flash attention, causal, 32x32 MFMA, swapped QK^T, BARRIER-FREE main loop.
// Both MFMA operands are lane-private row reads -> gather K and V^T fragments
// DIRECTLY from global (L1 catches the 8x/line reuse). No K/V LDS, no staging,
// no in-loop syncs: 4 wave-pairs per block free-run over tiles t≡pair (mod 4);
// one __syncthreads before the LDS flash-combine.
// Scores arrive pre-scaled by 0.125*log2(e) (folded into Wq) -> softmax via exp2.
__global__ __launch_bounds__(512, 2) void attn_fwd(
    const u16* __restrict__ Qp, const u16* __restrict__ Kp, const u16* __restrict__ Vt,
    u16* __restrict__ AO)
{
  __shared__ float comb_s[4][64 * 64];   // 64KB f32 O^T partials per pair
  __shared__ float lds_ml[4][64][2];     // 2KB
  const int tid = threadIdx.x;
  const int lane = tid & 63;
  const int wv = tid >> 6;
  const int pair = wv >> 1;
  const int wpair = wv & 1;
  const int ql = lane & 31;
  const int h = lane >> 5;
  const int qt = (NQ - 1) - (blockIdx.x >> 5);  // LPT; bh = bid&31 keeps bh%8 == XCD
  const int bh = blockIdx.x & 31;
  const int b = bh >> 4;
  const int hh = bh & 15;
  const int q0 = qt * 64;
  const size_t baseQK = (size_t)b * S_LEN * DM + hh * DK;
  const size_t baseV  = (size_t)hh * DK * MS + (size_t)b * S_LEN;

  const int qq = wpair * 32 + ql;
  const int qg = q0 + qq;

  bf16x8 qf[4];
#pragma unroll
  for (int ks = 0; ks < 4; ++ks)
    qf[ks] = *(const bf16x8*)&Qp[baseQK + (size_t)qg * DM + ks * 16 + h * 8];

  f32x16 ot[2];
#pragma unroll
  for (int n = 0; n < 2; ++n)
#pragma unroll
    for (int r = 0; r < 16; ++r) ot[n][r] = 0.f;
  float mrun = -1e30f, lrun = 0.f;

  for (int tt = pair; tt <= qt; tt += 4) {
    const int kv0 = tt * 64;

    // ---- K gather (lane-private rows, 16B each) ----
    bf16x8 kf[2][4];
#pragma unroll
    for (int c = 0; c < 2; ++c)
#pragma unroll
      for (int ks = 0; ks < 4; ++ks)
        kf[c][ks] = *(const bf16x8*)&Kp[baseQK + (size_t)(kv0 + c * 32 + ql) * DM + (2 * ks + h) * 8];

    // ---- QK^T (swapped): S^T[kv][q] ----
    f32x16 st[2];
    __builtin_amdgcn_s_setprio(1);
#pragma unroll
    for (int c = 0; c < 2; ++c) {
#pragma unroll
      for (int r = 0; r < 16; ++r) st[c][r] = 0.f;
#pragma unroll
      for (int ks = 0; ks < 4; ++ks)
        st[c] = __builtin_amdgcn_mfma_f32_32x32x16_bf16(kf[c][ks], qf[ks], st[c], 0, 0, 0);
    }
    __builtin_amdgcn_s_setprio(0);

    // ---- V gather issued now: flies under softmax ----
    bf16x8 vf[2][4];
#pragma unroll
    for (int n = 0; n < 2; ++n)
#pragma unroll
      for (int kst = 0; kst < 4; ++kst)
        vf[n][kst] = *(const bf16x8*)&Vt[baseV + (size_t)(n * 32 + ql) * MS + kv0 + (2 * kst + h) * 8];

    // ---- causal mask on diagonal tile (scores already in log2 domain) ----
    const bool diag = (tt == qt);
    if (diag) {
#pragma unroll
      for (int c = 0; c < 2; ++c)
#pragma unroll
        for (int r = 0; r < 16; ++r) {
          int kvg = kv0 + c * 32 + (r & 3) + 8 * (r >> 2) + 4 * h;
          if (kvg > qg) st[c][r] = -1e30f;
        }
    }

    // ---- online softmax, log2 domain, per-lane scalar m/l ----
    float mt = st[0][0];
#pragma unroll
    for (int c = 0; c < 2; ++c)
#pragma unroll
      for (int r = 0; r < 16; ++r) mt = fmaxf(mt, st[c][r]);
    mt = fmaxf(mt, __int_as_float(__shfl_xor(__float_as_int(mt), 32, 64)));

    if (!__all(mt <= mrun + 8.0f)) {     // T13 defer-max (log2 units)
      float mnew = fmaxf(mrun, mt);
      float corr = exp2f(mrun - mnew);
      lrun *= corr;
#pragma unroll
      for (int n = 0; n < 2; ++n)
#pragma unroll
        for (int r = 0; r < 16; ++r) ot[n][r] *= corr;
      mrun = mnew;
    }

    float ls = 0.f;
#pragma unroll
    for (int c = 0; c < 2; ++c)
#pragma unroll
      for (int r = 0; r < 16; ++r) {
        float p = exp2f(st[c][r] - mrun);
        st[c][r] = p;
        ls += p;
      }
    ls += __int_as_float(__shfl_xor(__float_as_int(ls), 32, 64));
    lrun += ls;

    // ---- PV: O^T += V^T * P (pack bf16 + half-swap inline) ----
#pragma unroll
    for (int kst = 0; kst < 4; ++kst) {
      const int c = kst >> 1, k1 = kst & 1;
      u32 pkg[4];
#pragma unroll
      for (int g4 = 0; g4 < 4; ++g4)
        pkg[g4] = cvtpk_bf16(st[c][2 * (4 * k1 + g4)], st[c][2 * (4 * k1 + g4) + 1]);
      u32 w[4];
#pragma unroll
      for (int par = 0; par < 2; ++par) {
        u32 x = pkg[par];
        u32 y = pkg[2 + par];
        u32 tt2 = h ? x : y;
        u32 tp = (u32)__shfl_xor((int)tt2, 32, 64);
        w[par]     = h ? tp : x;
        w[par + 2] = h ? y : tp;
      }
      union { u32 u[4]; bf16x8 v; } pb;
      pb.u[0] = w[0]; pb.u[1] = w[1]; pb.u[2] = w[2]; pb.u[3] = w[3];
      __builtin_amdgcn_s_setprio(1);
#pragma unroll
      for (int n = 0; n < 2; ++n)
        ot[n] = __builtin_amdgcn_mfma_f32_32x32x16_bf16(vf[n][kst], pb.v, ot[n], 0, 0, 0);
      __builtin_amdgcn_s_setprio(0);
    }
  }

  // ---- flash-combine of 4 pair-partials ----
  {
    float* comb = comb_s[pair];          // 64 d x 64 q f32, q swizzled by d
#pragma unroll
    for (int n = 0; n < 2; ++n)
#pragma unroll
      for (int r = 0; r < 16; ++r) {
        int d = 32 * n + (r & 3) + 8 * (r >> 2) + 4 * h;
        comb[d * 64 + (qq ^ ((d & 7) << 3))] = ot[n][r];
      }
    if (h == 0) { lds_ml[pair][qq][0] = mrun; lds_ml[pair][qq][1] = lrun; }
  }
  __syncthreads();
  {
    const int q = tid >> 3;
    const int d0 = (tid & 7) * 8;
    float m0 = lds_ml[0][q][0], m1 = lds_ml[1][q][0];
    float m2 = lds_ml[2][q][0], m3 = lds_ml[3][q][0];
    float mg = fmaxf(fmaxf(m0, m1), fmaxf(m2, m3));
    float w0 = exp2f(m0 - mg), w1 = exp2f(m1 - mg);
    float w2 = exp2f(m2 - mg), w3 = exp2f(m3 - mg);
    float lsum = w0 * lds_ml[0][q][1] + w1 * lds_ml[1][q][1]
               + w2 * lds_ml[2][q][1] + w3 * lds_ml[3][q][1];
    float inv = 1.0f / lsum;
    const float* c0 = comb_s[0];
    const float* c1 = comb_s[1];
    const float* c2 = comb_s[2];
    const float* c3 = comb_s[3];
    u32 o4[4];
#pragma unroll
    for (int ii = 0; ii < 4; ++ii) {
      int da = d0 + 2 * ii, db = da + 1;
      int ia = da * 64 + (q ^ ((da & 7) << 3));
      int ib = db * 64 + (q ^ ((db & 7) << 3));
      float va = w0 * c0[ia] + w1 * c1[ia] + w2 * c2[ia] + w3 * c3[ia];
      float vb = w0 * c0[ib] + w1 * c1[ib] + w2 * c2[ib] + w3 * c3[ib];
      o4[ii] = cvtpk_bf16(va * inv, vb * inv);
    }
    uint4 outv;
    outv.x = o4[0]; outv.y = o4[1]; outv.z = o4[2]; outv.w = o4[3];
    *(uint4*)&AO[baseQK + (size_t)(q0 + q) * DM + d0] = outv;
  }
}

extern "C" void kernel_launch(void* const* d_in, const int* in_sizes, int n_in,
                              void* d_out, int out_size, void* d_ws, size_t ws_size,
                              hipStream_t stream) {
  const float* q  = (const float*)d_in[0];
  const float* k  = (const float*)d_in[1];
  const float* v  = (const float*)d_in[2];
  // d_in[3] = mask : deterministic causal tril, applied analytically
  const float* wq = (const float*)d_in[4];
  const float* wk = (const float*)d_in[5];
  const float* wv = (const float*)d_in[6];
  const float* wo = (const float*)d_in[7];

  const size_t nIn = (size_t)MS * DM;
  const size_t nW  = (size_t)DM * DM;

  u16* ws = (u16*)d_ws;
  u16* qb  = ws; ws += nIn;
  u16* kb  = ws; ws += nIn;
  u16* vb  = ws; ws += nIn;
  u16* wqb = ws; ws += nW;
  u16* wkb = ws; ws += nW;
  u16* wvb = ws; ws += nW;
  u16* wob = ws; ws += nW;
  u16* Qp  = ws; ws += nIn;
  u16* Kp  = ws; ws += nIn;
  u16* Vt  = ws; ws += nIn;   // [DM][MS] transposed V projection
  u16* AO  = ws; ws += nIn;

  CvtArgs ca;
  const float QSCL = 0.125f * 1.44269504089f;   // fold 1/sqrt(dk) * log2(e) into Wq
  ca.src[0] = q;  ca.dst[0] = qb;  ca.n4[0] = (int)(nIn / 4); ca.scl[0] = 1.f;
  ca.src[1] = k;  ca.dst[1] = kb;  ca.n4[1] = (int)(nIn / 4); ca.scl[1] = 1.f;
  ca.src[2] = v;  ca.dst[2] = vb;  ca.n4[2] = (int)(nIn / 4); ca.scl[2] = 1.f;
  ca.src[3] = wq; ca.dst[3] = wqb; ca.n4[3] = (int)(nW / 4);  ca.scl[3] = QSCL;
  ca.src[4] = wk; ca.dst[4] = wkb; ca.n4[4] = (int)(nW / 4);  ca.scl[4] = 1.f;
  ca.src[5] = wv; ca.dst[5] = wvb; ca.n4[5] = (int)(nW / 4);  ca.scl[5] = 1.f;
  ca.src[6] = wo; ca.dst[6] = wob; ca.n4[6] = (int)(nW / 4);  ca.scl[6] = 1.f;
  cvt_all<<<dim3(256, 7), 256, 0, stream>>>(ca);

  gemm_bt<true,64><<<dim3(8, 64), 256, 0, stream>>>(qb, wqb, Qp, MS, DM, DM);
  gemm_bt<true,64><<<dim3(8, 64), 256, 0, stream>>>(kb, wkb, Kp, MS, DM, DM);
  // V^T = Wv * X^T  -> [DM][MS], the layout attention wants
  gemm_bt<true,64><<<dim3(32, 16), 256, 0, stream>>>(wvb, vb, Vt, DM, MS, DM);

  attn_fwd<<<dim3(NQ * 32), 512, 0, stream>>>(Qp, Kp, Vt, AO);

  gemm_bt<false,64><<<dim3(8, 64), 256, 0, stream>>>(AO, wob, d_out, MS, DM, DM);
}

// Round 8
// 146.578 us; speedup vs baseline: 1.2378x; 1.2378x over previous
//
#include <hip/hip_runtime.h>
#include <math.h>

#define S_LEN 2048
#define DM 1024
#define NH 16
#define DK 64
#define BATCH 2
#define MS (BATCH*S_LEN)
#define NQ32 64        // S_LEN/32 q-tiles

typedef __attribute__((ext_vector_type(8))) short bf16x8;
typedef __attribute__((ext_vector_type(4))) float f32x4;
typedef __attribute__((ext_vector_type(16))) float f32x16;
typedef unsigned short u16;
typedef unsigned int u32;

__device__ __forceinline__ u16 f2b(float f) {
  union { float f; u32 u; } x; x.f = f;
  u32 r = x.u + 0x7FFFu + ((x.u >> 16) & 1u);
  return (u16)(r >> 16);
}

__device__ __forceinline__ u32 cvtpk_bf16(float lo, float hi) {
  u32 r;
  asm volatile("v_cvt_pk_bf16_f32 %0, %1, %2" : "=v"(r) : "v"(lo), "v"(hi));
  return r;
}

struct CvtArgs {
  const float* src[7];
  u16* dst[7];
  float scl[7];
  int n4[7];
};

__global__ void cvt_all(CvtArgs a) {
  const int seg = blockIdx.y;
  const float* __restrict__ in = a.src[seg];
  u16* __restrict__ out = a.dst[seg];
  const float s = a.scl[seg];
  const int n4 = a.n4[seg];
  int idx = blockIdx.x * blockDim.x + threadIdx.x;
  int stride = gridDim.x * blockDim.x;
  for (int i = idx; i < n4; i += stride) {
    float4 v = ((const float4*)in)[i];
    ushort4 o;
    o.x = f2b(v.x * s); o.y = f2b(v.y * s); o.z = f2b(v.z * s); o.w = f2b(v.w * s);
    ((ushort4*)out)[i] = o;
  }
}

__device__ __forceinline__ void gload_lds16(const u16* g, u16* l) {
  __builtin_amdgcn_global_load_lds((const __attribute__((address_space(1))) u32*)g,
                                   (__attribute__((address_space(3))) u32*)l, 16, 0, 0);
}

// ---- GEMM body: C[M,N] = A[M,K]*B[N,K]^T, R6-verified 2-barrier single-buffer ----
template<bool OUT_BF16, int BM>
__device__ __forceinline__ void gemm_body(
    const u16* __restrict__ A, const u16* __restrict__ B, void* __restrict__ Cout,
    int M, int N, int K, int bx, int by, u16* lsA, u16* lsB)
{
  constexpr int MF = BM / 32;
  const int tid = threadIdx.x;
  const int lane = tid & 63;
  const int wid = tid >> 6;
  const int wr = wid >> 1, wc = wid & 1;
  const int m0 = by * BM, n0 = bx * 128;

  f32x4 acc[MF][4];
#pragma unroll
  for (int i = 0; i < MF; ++i)
#pragma unroll
    for (int j = 0; j < 4; ++j) acc[i][j] = (f32x4){0.f, 0.f, 0.f, 0.f};

  const int ntiles = K >> 5;

#pragma unroll
  for (int i = 0; i < BM/64; ++i) {
    int u = tid + i * 256;
    gload_lds16(A + (size_t)(m0 + (u >> 2)) * K + (u & 3) * 8, &lsA[u * 8]);
  }
#pragma unroll
  for (int i = 0; i < 2; ++i) {
    int u = tid + i * 256;
    gload_lds16(B + (size_t)(n0 + (u >> 2)) * K + (u & 3) * 8, &lsB[u * 8]);
  }

  for (int kt = 0; kt < ntiles; ++kt) {
    __syncthreads();
    bf16x8 af[MF], bfr[4];
    const int kOff = (lane >> 4) * 8;
#pragma unroll
    for (int m = 0; m < MF; ++m)
      af[m] = *(const bf16x8*)&lsA[(wr * (BM/2) + m * 16 + (lane & 15)) * 32 + kOff];
#pragma unroll
    for (int n = 0; n < 4; ++n)
      bfr[n] = *(const bf16x8*)&lsB[(wc * 64 + n * 16 + (lane & 15)) * 32 + kOff];
    __syncthreads();
    if (kt + 1 < ntiles) {
      int k0 = (kt + 1) << 5;
#pragma unroll
      for (int i = 0; i < BM/64; ++i) {
        int u = tid + i * 256;
        gload_lds16(A + (size_t)(m0 + (u >> 2)) * K + k0 + (u & 3) * 8, &lsA[u * 8]);
      }
#pragma unroll
      for (int i = 0; i < 2; ++i) {
        int u = tid + i * 256;
        gload_lds16(B + (size_t)(n0 + (u >> 2)) * K + k0 + (u & 3) * 8, &lsB[u * 8]);
      }
    }
#pragma unroll
    for (int m = 0; m < MF; ++m)
#pragma unroll
      for (int n = 0; n < 4; ++n)
        acc[m][n] = __builtin_amdgcn_mfma_f32_16x16x32_bf16(af[m], bfr[n], acc[m][n], 0, 0, 0);
  }

  const int rbase = m0 + wr * (BM/2) + ((lane >> 4) << 2);
  const int cbase = n0 + wc * 64 + (lane & 15);
#pragma unroll
  for (int m = 0; m < MF; ++m)
#pragma unroll
    for (int n = 0; n < 4; ++n)
#pragma unroll
      for (int j = 0; j < 4; ++j) {
        int r = rbase + m * 16 + j;
        int c = cbase + n * 16;
        if (OUT_BF16)
          ((u16*)Cout)[(size_t)r * N + c] = f2b(acc[m][n][j]);
        else
          ((float*)Cout)[(size_t)r * N + c] = acc[m][n][j];
      }
}

struct G3Args {
  const u16* A[3];
  const u16* B[3];
  u16* C[3];
  int M[3], N[3];
};

// three independent projection GEMMs in one launch: 512 blocks each
__global__ __launch_bounds__(256) void gemm_qkv(G3Args g) {
  __shared__ u16 lsA[64*32];
  __shared__ u16 lsB[128*32];
  const int bid = blockIdx.x;
  const int gi = bid >> 9;            // 0,1,2
  const int f = bid & 511;
  const int gx = (gi == 2) ? 32 : 8;  // Vt gemm has N=4096 -> 32 col-blocks
  gemm_body<true,64>(g.A[gi], g.B[gi], g.C[gi], g.M[gi], g.N[gi], 1024,
                     f % gx, f / gx, lsA, lsB);
}

__global__ __launch_bounds__(256) void gemm_out(
    const u16* __restrict__ A, const u16* __restrict__ B, float* __restrict__ C) {
  __shared__ u16 lsA[64*32];
  __shared__ u16 lsB[128*32];
  gemm_body<false,64>(A, B, C, MS, DM, DM, blockIdx.x, blockIdx.y, lsA, lsB);
}

// ---- Flash attention: wave-autonomous, KVBLK=32, q-tile=32, ZERO in-loop barriers.
// Block = 4 waves KV-splitting one (b,h,qtile32): wave w does tiles tt≡w (mod 4) into
// private (m,l,O^T). Each wave stages K/V into its OWN 8KB LDS slice via global_load_lds
// (pre-swizzled source + linear dest + swizzled read); waits are wave-local s_waitcnt.
// One __syncthreads total (flash-combine). Scores pre-scaled by 0.125*log2e -> exp2.
__global__ __launch_bounds__(256) void attn_fwd(
    const u16* __restrict__ Qp, const u16* __restrict__ Kp, const u16* __restrict__ Vt,
    u16* __restrict__ AO)
{
  __shared__ __align__(16) u16 lds_kv[4][4096];   // per wave: K[32][64] @0, V^T[64][32] @2048
  __shared__ float lds_ml[4][32][2];
  const int tid = threadIdx.x;
  const int lane = tid & 63;
  const int w = tid >> 6;
  const int ql = lane & 31;
  const int h = lane >> 5;
  const int bid = blockIdx.x;
  const int j = (NQ32 - 1) - (bid >> 5);    // q-tile 0..63, LPT (long first)
  const int bh = bid & 31;
  const int b = bh >> 4;
  const int hh = bh & 15;
  const int q0 = j * 32;
  const int qg = q0 + ql;
  const size_t baseQK = (size_t)b * S_LEN * DM + hh * DK;
  const size_t baseV  = (size_t)hh * DK * MS + (size_t)b * S_LEN;

  u16* const lk = lds_kv[w];
  u16* const lv = lds_kv[w] + 2048;

  // Q fragments (B-operand): lane holds Q[qg][16ks+8h+e]
  bf16x8 qf[4];
#pragma unroll
  for (int ks = 0; ks < 4; ++ks)
    qf[ks] = *(const bf16x8*)&Qp[baseQK + (size_t)qg * DM + ks * 16 + h * 8];

  f32x16 ot[2];
#pragma unroll
  for (int n = 0; n < 2; ++n)
#pragma unroll
    for (int r = 0; r < 16; ++r) ot[n][r] = 0.f;
  float mrun = -1e30f, lrun = 0.f;

  // K tile: 32 rows x 8 chunks(16B); V^T tile: 64 rows x 4 chunks(16B). 256 chunks each,
  // 4 gload_lds instructions per tile per matrix. Source chunk-col XOR-swizzled.
#define STAGE(KV0) do { \
    _Pragma("unroll") \
    for (int jj = 0; jj < 4; ++jj) { \
      int c = jj * 64 + lane; \
      int kr = c >> 3, kc = c & 7; \
      gload_lds16(Kp + baseQK + (size_t)((KV0) + kr) * DM + ((kc ^ (kr & 7)) * 8), &lk[c * 8]); \
      int vr = c >> 2, vc = c & 3; \
      gload_lds16(Vt + baseV + (size_t)vr * MS + (KV0) + ((vc ^ (vr & 3)) * 8), &lv[c * 8]); \
    } \
  } while (0)

  if (w <= j) STAGE(w * 32);

  for (int tt = w; tt <= j; tt += 4) {
    asm volatile("s_waitcnt vmcnt(0)" ::: "memory");   // wave-local: stage landed

    bf16x8 kf[4], vf[2][2];
#pragma unroll
    for (int ks = 0; ks < 4; ++ks)
      kf[ks] = *(const bf16x8*)&lk[(ql * 8 + ((2 * ks + h) ^ (ql & 7))) * 8];
#pragma unroll
    for (int n = 0; n < 2; ++n)
#pragma unroll
      for (int kst = 0; kst < 2; ++kst)
        vf[n][kst] = *(const bf16x8*)&lv[((n * 32 + ql) * 4 + ((2 * kst + h) ^ (ql & 3))) * 8];
    asm volatile("s_waitcnt lgkmcnt(0)" ::: "memory"); // reads retired -> safe to overwrite
    if (tt + 4 <= j) STAGE((tt + 4) * 32);             // flies under compute

    // QK^T (swapped): S^T[32 kv][32 q]
    f32x16 st;
#pragma unroll
    for (int r = 0; r < 16; ++r) st[r] = 0.f;
    __builtin_amdgcn_s_setprio(1);
#pragma unroll
    for (int ks = 0; ks < 4; ++ks)
      st = __builtin_amdgcn_mfma_f32_32x32x16_bf16(kf[ks], qf[ks], st, 0, 0, 0);
    __builtin_amdgcn_s_setprio(0);

    // causal mask, diagonal tile only (tile tt==j is the triangular one)
    if (tt == j) {
#pragma unroll
      for (int r = 0; r < 16; ++r) {
        int kvg = j * 32 + (r & 3) + 8 * (r >> 2) + 4 * h;
        if (kvg > qg) st[r] = -1e30f;
      }
    }

    // online softmax (log2 domain), per-lane scalar m/l
    float mt = st[0];
#pragma unroll
    for (int r = 1; r < 16; ++r) mt = fmaxf(mt, st[r]);
    mt = fmaxf(mt, __int_as_float(__shfl_xor(__float_as_int(mt), 32, 64)));

    if (!__all(mt <= mrun + 8.0f)) {     // T13 defer-max
      float mnew = fmaxf(mrun, mt);
      float corr = exp2f(mrun - mnew);
      lrun *= corr;
#pragma unroll
      for (int n = 0; n < 2; ++n)
#pragma unroll
        for (int r = 0; r < 16; ++r) ot[n][r] *= corr;
      mrun = mnew;
    }

    float ls = 0.f;
#pragma unroll
    for (int r = 0; r < 16; ++r) {
      float p = exp2f(st[r] - mrun);
      st[r] = p;
      ls += p;
    }
    ls += __int_as_float(__shfl_xor(__float_as_int(ls), 32, 64));
    lrun += ls;

    // PV: O^T += V^T * P (pack bf16 + half-swap, R6-verified index mapping)
#pragma unroll
    for (int kst = 0; kst < 2; ++kst) {
      u32 pkg[4];
#pragma unroll
      for (int g4 = 0; g4 < 4; ++g4)
        pkg[g4] = cvtpk_bf16(st[8 * kst + 2 * g4], st[8 * kst + 2 * g4 + 1]);
      u32 wv_[4];
#pragma unroll
      for (int par = 0; par < 2; ++par) {
        u32 x = pkg[par];
        u32 y = pkg[2 + par];
        u32 t2 = h ? x : y;
        u32 tp = (u32)__shfl_xor((int)t2, 32, 64);
        wv_[par]     = h ? tp : x;
        wv_[par + 2] = h ? y : tp;
      }
      union { u32 u[4]; bf16x8 v; } pb;
      pb.u[0] = wv_[0]; pb.u[1] = wv_[1]; pb.u[2] = wv_[2]; pb.u[3] = wv_[3];
      __builtin_amdgcn_s_setprio(1);
#pragma unroll
      for (int n = 0; n < 2; ++n)
        ot[n] = __builtin_amdgcn_mfma_f32_32x32x16_bf16(vf[n][kst], pb.v, ot[n], 0, 0, 0);
      __builtin_amdgcn_s_setprio(0);
    }
  }

  // ---- flash-combine of 4 wave-partials (reuse this wave's K/V LDS: 8KB = 64x32 f32) ----
  {
    float* comb = (float*)lds_kv[w];
#pragma unroll
    for (int n = 0; n < 2; ++n)
#pragma unroll
      for (int r = 0; r < 16; ++r) {
        int d = 32 * n + (r & 3) + 8 * (r >> 2) + 4 * h;
        comb[d * 32 + (ql ^ (d & 31))] = ot[n][r];
      }
    if (h == 0) { lds_ml[w][ql][0] = mrun; lds_ml[w][ql][1] = lrun; }
  }
  __syncthreads();
  {
    const int q = tid >> 3;            // 0..31
    const int d0 = (tid & 7) * 8;
    float m0 = lds_ml[0][q][0], m1 = lds_ml[1][q][0];
    float m2 = lds_ml[2][q][0], m3 = lds_ml[3][q][0];
    float mg = fmaxf(fmaxf(m0, m1), fmaxf(m2, m3));
    float w0 = exp2f(m0 - mg), w1 = exp2f(m1 - mg);
    float w2 = exp2f(m2 - mg), w3 = exp2f(m3 - mg);
    float lsum = w0 * lds_ml[0][q][1] + w1 * lds_ml[1][q][1]
               + w2 * lds_ml[2][q][1] + w3 * lds_ml[3][q][1];
    float inv = 1.0f / lsum;
    const float* c0 = (const float*)lds_kv[0];
    const float* c1 = (const float*)lds_kv[1];
    const float* c2 = (const float*)lds_kv[2];
    const float* c3 = (const float*)lds_kv[3];
    u32 o4[4];
#pragma unroll
    for (int ii = 0; ii < 4; ++ii) {
      int da = d0 + 2 * ii, db = da + 1;
      int ia = da * 32 + (q ^ (da & 31));
      int ib = db * 32 + (q ^ (db & 31));
      float va = w0 * c0[ia] + w1 * c1[ia] + w2 * c2[ia] + w3 * c3[ia];
      float vb = w0 * c0[ib] + w1 * c1[ib] + w2 * c2[ib] + w3 * c3[ib];
      o4[ii] = cvtpk_bf16(va * inv, vb * inv);
    }
    uint4 outv;
    outv.x = o4[0]; outv.y = o4[1]; outv.z = o4[2]; outv.w = o4[3];
    *(uint4*)&AO[baseQK + (size_t)(q0 + q) * DM + d0] = outv;
  }
#undef STAGE
}

extern "C" void kernel_launch(void* const* d_in, const int* in_sizes, int n_in,
                              void* d_out, int out_size, void* d_ws, size_t ws_size,
                              hipStream_t stream) {
  const float* q  = (const float*)d_in[0];
  const float* k  = (const float*)d_in[1];
  const float* v  = (const float*)d_in[2];
  // d_in[3] = mask : deterministic causal tril, applied analytically
  const float* wq = (const float*)d_in[4];
  const float* wk = (const float*)d_in[5];
  const float* wv = (const float*)d_in[6];
  const float* wo = (const float*)d_in[7];

  const size_t nIn = (size_t)MS * DM;
  const size_t nW  = (size_t)DM * DM;

  u16* ws = (u16*)d_ws;
  u16* qb  = ws; ws += nIn;
  u16* kb  = ws; ws += nIn;
  u16* vb  = ws; ws += nIn;
  u16* wqb = ws; ws += nW;
  u16* wkb = ws; ws += nW;
  u16* wvb = ws; ws += nW;
  u16* wob = ws; ws += nW;
  u16* Qp  = ws; ws += nIn;
  u16* Kp  = ws; ws += nIn;
  u16* Vt  = ws; ws += nIn;   // [DM][MS] transposed V projection
  u16* AO  = ws; ws += nIn;

  CvtArgs ca;
  const float QSCL = 0.125f * 1.44269504089f;   // fold 1/sqrt(dk)*log2e into Wq
  ca.src[0] = q;  ca.dst[0] = qb;  ca.n4[0] = (int)(nIn / 4); ca.scl[0] = 1.f;
  ca.src[1] = k;  ca.dst[1] = kb;  ca.n4[1] = (int)(nIn / 4); ca.scl[1] = 1.f;
  ca.src[2] = v;  ca.dst[2] = vb;  ca.n4[2] = (int)(nIn / 4); ca.scl[2] = 1.f;
  ca.src[3] = wq; ca.dst[3] = wqb; ca.n4[3] = (int)(nW / 4);  ca.scl[3] = QSCL;
  ca.src[4] = wk; ca.dst[4] = wkb; ca.n4[4] = (int)(nW / 4);  ca.scl[4] = 1.f;
  ca.src[5] = wv; ca.dst[5] = wvb; ca.n4[5] = (int)(nW / 4);  ca.scl[5] = 1.f;
  ca.src[6] = wo; ca.dst[6] = wob; ca.n4[6] = (int)(nW / 4);  ca.scl[6] = 1.f;
  cvt_all<<<dim3(256, 7), 256, 0, stream>>>(ca);

  // merged projections: Q-proj, K-proj, Vt-proj (Vt = Wv * X^T -> [DM][MS])
  G3Args g3;
  g3.A[0] = qb;  g3.B[0] = wqb; g3.C[0] = Qp; g3.M[0] = MS; g3.N[0] = DM;
  g3.A[1] = kb;  g3.B[1] = wkb; g3.C[1] = Kp; g3.M[1] = MS; g3.N[1] = DM;
  g3.A[2] = wvb; g3.B[2] = vb;  g3.C[2] = Vt; g3.M[2] = DM; g3.N[2] = MS;
  gemm_qkv<<<dim3(1536), 256, 0, stream>>>(g3);

  attn_fwd<<<dim3(NQ32 * 32), 256, 0, stream>>>(Qp, Kp, Vt, AO);

  gemm_out<<<dim3(8, 64), 256, 0, stream>>>(AO, wob, (float*)d_out);
}